// Round 18
// baseline (128.204 us; speedup 1.0000x reference)
//
#include <hip/hip_runtime.h>
#include <cmath>

#define BATCH 32
#define CCH 512
#define HW 4096
#define KCL 17

typedef __attribute__((ext_vector_type(8))) short short8;
typedef __attribute__((ext_vector_type(16))) float f32x16;
typedef __attribute__((ext_vector_type(4))) float f32x4;

__device__ __forceinline__ unsigned pack_bf16(float a, float b) {
  unsigned ua = (__float_as_uint(a) + 0x8000u) >> 16;
  unsigned ub = (__float_as_uint(b) + 0x8000u) & 0xFFFF0000u;
  return ua | ub;
}
__device__ __forceinline__ f32x4 ntload4(const float* p) {
  return __builtin_nontemporal_load(reinterpret_cast<const f32x4*>(p));
}

// ws layout (bytes)
#define WT_OFF 0
#define WT_BYTES (CCH * 20 * 4)                    // 40960
#define SIG_OFF WT_BYTES
#define SIG_BYTES ((size_t)BATCH * 32 * HW * 2)    // 8388608   bf16 [b][32pad][4096]
#define XBF_OFF (SIG_OFF + SIG_BYTES)
#define XBF_BYTES ((size_t)BATCH * CCH * HW * 2)   // 134217728 bf16 [b][ch][4096]
#define WS_NEED (XBF_OFF + XBF_BYTES)              // ~143 MB (ws ~1 GB)

#define K12_LDS (4 * KCL * 512 * 4)                // 139264 B f32 reduce tree

// K0: wT fill + zero out_g (g accumulated via atomics in k12)
__global__ void k0_setup(const float* __restrict__ w, float* __restrict__ wT,
                         float* __restrict__ out_g) {
  int c = threadIdx.x;  // 512
  #pragma unroll
  for (int k = 0; k < 20; ++k) wT[c * 20 + k] = (k < KCL) ? w[k * CCH + c] : 0.f;
  if (c < BATCH * KCL) out_g[c] = 0.f;
  if (c < BATCH * KCL - 512) out_g[512 + c] = 0.f;
}

// K12: fused cam+sigmoid+xbf, 16-B-wide VMEM everywhere. Block = (b, 512-px
// slice), 512 thr: slab = wave id (8 slabs x 64 ch, wave-uniform scalar w),
// pxg = lane (64 x 8 px). Per row: 2 dwordx4 loads + 1 dwordx4 store.
// Burst pipeline: next-pair loads issue before current-pair compute+stores.
__global__ __launch_bounds__(512, 1)
void k12_cam_sig(const float* __restrict__ x, const float* __restrict__ wT,
                 const float* __restrict__ bias, float* __restrict__ out_g,
                 unsigned short* __restrict__ xbf, unsigned short* __restrict__ sig) {
  extern __shared__ float R[];  // [4][17][512] f32
  const int t = threadIdx.x;
  const int slab = __builtin_amdgcn_readfirstlane(t >> 6);  // 0..7 = wave id
  const int pxg = t & 63;
  const int b = blockIdx.x >> 3;
  const int slice = blockIdx.x & 7;
  const int px = slice * 512 + pxg * 8;
  const float* xp = x + ((size_t)(b * CCH + slab * 64)) * HW + px;
  unsigned short* xbp = xbf + ((size_t)(b * CCH + slab * 64)) * HW + px;

  float cam[KCL][8];
  #pragma unroll
  for (int k = 0; k < KCL; ++k)
    #pragma unroll
    for (int i = 0; i < 8; ++i) cam[k][i] = 0.f;

  f32x4 v0[2][2], v1[2][2];
  #pragma unroll
  for (int j = 0; j < 2; ++j) {
    v0[j][0] = ntload4(xp + (size_t)j * HW);
    v0[j][1] = ntload4(xp + (size_t)j * HW + 4);
  }

  #pragma unroll 1
  for (int gp = 0; gp < 16; ++gp) {
    const int c0 = gp * 4;
    // issue loads for rows c0+2, c0+3
    #pragma unroll
    for (int j = 0; j < 2; ++j) {
      v1[j][0] = ntload4(xp + (size_t)(c0 + 2 + j) * HW);
      v1[j][1] = ntload4(xp + (size_t)(c0 + 2 + j) * HW + 4);
    }
    // compute + store rows c0, c0+1
    #pragma unroll
    for (int j = 0; j < 2; ++j) {
      const f32x4 a = v0[j][0], q = v0[j][1];
      const float* wr = wT + (slab * 64 + c0 + j) * 20;  // scalar (slab SGPR)
      #pragma unroll
      for (int k = 0; k < KCL; ++k) {
        const float wk = wr[k];
        cam[k][0] = fmaf(wk, a.x, cam[k][0]);
        cam[k][1] = fmaf(wk, a.y, cam[k][1]);
        cam[k][2] = fmaf(wk, a.z, cam[k][2]);
        cam[k][3] = fmaf(wk, a.w, cam[k][3]);
        cam[k][4] = fmaf(wk, q.x, cam[k][4]);
        cam[k][5] = fmaf(wk, q.y, cam[k][5]);
        cam[k][6] = fmaf(wk, q.z, cam[k][6]);
        cam[k][7] = fmaf(wk, q.w, cam[k][7]);
      }
      uint4 u;
      u.x = pack_bf16(a.x, a.y);
      u.y = pack_bf16(a.z, a.w);
      u.z = pack_bf16(q.x, q.y);
      u.w = pack_bf16(q.z, q.w);
      *reinterpret_cast<uint4*>(xbp + (size_t)(c0 + j) * HW) = u;
    }
    // issue loads for rows c0+4, c0+5
    if (gp < 15) {
      #pragma unroll
      for (int j = 0; j < 2; ++j) {
        v0[j][0] = ntload4(xp + (size_t)(c0 + 4 + j) * HW);
        v0[j][1] = ntload4(xp + (size_t)(c0 + 4 + j) * HW + 4);
      }
    }
    // compute + store rows c0+2, c0+3
    #pragma unroll
    for (int j = 0; j < 2; ++j) {
      const f32x4 a = v1[j][0], q = v1[j][1];
      const float* wr = wT + (slab * 64 + c0 + 2 + j) * 20;
      #pragma unroll
      for (int k = 0; k < KCL; ++k) {
        const float wk = wr[k];
        cam[k][0] = fmaf(wk, a.x, cam[k][0]);
        cam[k][1] = fmaf(wk, a.y, cam[k][1]);
        cam[k][2] = fmaf(wk, a.z, cam[k][2]);
        cam[k][3] = fmaf(wk, a.w, cam[k][3]);
        cam[k][4] = fmaf(wk, q.x, cam[k][4]);
        cam[k][5] = fmaf(wk, q.y, cam[k][5]);
        cam[k][6] = fmaf(wk, q.z, cam[k][6]);
        cam[k][7] = fmaf(wk, q.w, cam[k][7]);
      }
      uint4 u;
      u.x = pack_bf16(a.x, a.y);
      u.y = pack_bf16(a.z, a.w);
      u.z = pack_bf16(q.x, q.y);
      u.w = pack_bf16(q.z, q.w);
      *reinterpret_cast<uint4*>(xbp + (size_t)(c0 + 2 + j) * HW) = u;
    }
  }

  // f32 reduce tree over 8 wave partials: 8 -> 4 -> 2 -> 1
  const int base = pxg * 8;
  if (slab >= 4) {
    float* Rb = R + (slab - 4) * (KCL * 512);
    #pragma unroll
    for (int k = 0; k < KCL; ++k) {
      *reinterpret_cast<float4*>(Rb + k * 512 + base) =
          make_float4(cam[k][0], cam[k][1], cam[k][2], cam[k][3]);
      *reinterpret_cast<float4*>(Rb + k * 512 + base + 4) =
          make_float4(cam[k][4], cam[k][5], cam[k][6], cam[k][7]);
    }
  }
  __syncthreads();
  if (slab < 4) {
    const float* Rb = R + slab * (KCL * 512);
    #pragma unroll
    for (int k = 0; k < KCL; ++k) {
      const float4 r0 = *reinterpret_cast<const float4*>(Rb + k * 512 + base);
      const float4 r1 = *reinterpret_cast<const float4*>(Rb + k * 512 + base + 4);
      cam[k][0] += r0.x; cam[k][1] += r0.y; cam[k][2] += r0.z; cam[k][3] += r0.w;
      cam[k][4] += r1.x; cam[k][5] += r1.y; cam[k][6] += r1.z; cam[k][7] += r1.w;
    }
  }
  __syncthreads();
  if (slab == 2 || slab == 3) {
    float* Rb = R + (slab - 2) * (KCL * 512);
    #pragma unroll
    for (int k = 0; k < KCL; ++k) {
      *reinterpret_cast<float4*>(Rb + k * 512 + base) =
          make_float4(cam[k][0], cam[k][1], cam[k][2], cam[k][3]);
      *reinterpret_cast<float4*>(Rb + k * 512 + base + 4) =
          make_float4(cam[k][4], cam[k][5], cam[k][6], cam[k][7]);
    }
  }
  __syncthreads();
  if (slab < 2) {
    const float* Rb = R + slab * (KCL * 512);
    #pragma unroll
    for (int k = 0; k < KCL; ++k) {
      const float4 r0 = *reinterpret_cast<const float4*>(Rb + k * 512 + base);
      const float4 r1 = *reinterpret_cast<const float4*>(Rb + k * 512 + base + 4);
      cam[k][0] += r0.x; cam[k][1] += r0.y; cam[k][2] += r0.z; cam[k][3] += r0.w;
      cam[k][4] += r1.x; cam[k][5] += r1.y; cam[k][6] += r1.z; cam[k][7] += r1.w;
    }
  }
  __syncthreads();
  if (slab == 1) {
    #pragma unroll
    for (int k = 0; k < KCL; ++k) {
      *reinterpret_cast<float4*>(R + k * 512 + base) =
          make_float4(cam[k][0], cam[k][1], cam[k][2], cam[k][3]);
      *reinterpret_cast<float4*>(R + k * 512 + base + 4) =
          make_float4(cam[k][4], cam[k][5], cam[k][6], cam[k][7]);
    }
  }
  __syncthreads();
  if (slab == 0) {
    const float inv = 1.f / 4096.f;
    #pragma unroll
    for (int k = 0; k < KCL; ++k) {
      const float4 r0 = *reinterpret_cast<const float4*>(R + k * 512 + base);
      const float4 r1 = *reinterpret_cast<const float4*>(R + k * 512 + base + 4);
      const float bk = bias[k];
      float cf[8];
      cf[0] = cam[k][0] + r0.x + bk; cf[1] = cam[k][1] + r0.y + bk;
      cf[2] = cam[k][2] + r0.z + bk; cf[3] = cam[k][3] + r0.w + bk;
      cf[4] = cam[k][4] + r1.x + bk; cf[5] = cam[k][5] + r1.y + bk;
      cf[6] = cam[k][6] + r1.z + bk; cf[7] = cam[k][7] + r1.w + bk;
      uint4 u;
      u.x = pack_bf16(1.f / (1.f + __expf(-cf[0])), 1.f / (1.f + __expf(-cf[1])));
      u.y = pack_bf16(1.f / (1.f + __expf(-cf[2])), 1.f / (1.f + __expf(-cf[3])));
      u.z = pack_bf16(1.f / (1.f + __expf(-cf[4])), 1.f / (1.f + __expf(-cf[5])));
      u.w = pack_bf16(1.f / (1.f + __expf(-cf[6])), 1.f / (1.f + __expf(-cf[7])));
      *reinterpret_cast<uint4*>(sig + ((size_t)(b * 32 + k)) * HW + px) = u;
      float gk = cf[0] + cf[1] + cf[2] + cf[3] + cf[4] + cf[5] + cf[6] + cf[7];
      #pragma unroll
      for (int o = 1; o < 64; o <<= 1) gk += __shfl_xor(gk, o, 64);
      if ((t & 63) == 0) atomicAdd(out_g + b * KCL + k, gk * inv);
    }
  }
}

// K3: sf[b,:,chs*32..+32] = (1/4096) * xbf[32ch rows] @ sigT. Barrier-free MFMA
// global-gather from L3-resident xbf+sig; one sync for the 8-wave K-reduce.
__global__ __launch_bounds__(512, 2)
void k3_sf(const unsigned short* __restrict__ xbf, const unsigned short* __restrict__ sig,
           float* __restrict__ out_sf) {
  __shared__ float P[8 * 1024];  // 32 KB K-reduce scratch
  // XCD-chunked bijective swizzle: 512 blocks, 64 per XCD -> same-b blocks cluster
  const int p = blockIdx.x;
  const int lid = (p & 7) * 64 + (p >> 3);
  const int b = lid >> 4;
  const int chs = lid & 15;
  const int t = threadIdx.x;
  const int lane = t & 63;
  const int wv = __builtin_amdgcn_readfirstlane(t >> 6);  // 0..7, K-split
  const int m = lane & 31;
  const int h = lane >> 5;

  const unsigned short* ap = xbf + ((size_t)(b * CCH + chs * 32 + m)) * HW;
  const unsigned short* bp = sig + ((size_t)(b * 32 + m)) * HW;

  f32x16 acc;
  #pragma unroll
  for (int i = 0; i < 16; ++i) acc[i] = 0.f;

  // wave wv covers px slots [wv*64, wv*64+64): 2-KB contiguous stream per row
  const int obase = (wv * 64 + h) * 8;
  #pragma unroll 4
  for (int i = 0; i < 32; ++i) {
    const int o = obase + i * 16;  // ushort offset
    const short8 a = *reinterpret_cast<const short8*>(ap + o);
    const short8 bb = *reinterpret_cast<const short8*>(bp + o);
    acc = __builtin_amdgcn_mfma_f32_32x32x16_bf16(a, bb, acc, 0, 0, 0);
  }

  // K-reduce across 8 waves (validated C-layout map)
  #pragma unroll
  for (int r = 0; r < 16; ++r) {
    const int chr = (r & 3) + 8 * (r >> 2) + 4 * h;
    P[wv * 1024 + m * 32 + chr] = acc[r];  // index = cls*32 + ch
  }
  __syncthreads();
  const float inv = 1.f / 4096.f;
  {
    float s = 0.f;
    #pragma unroll
    for (int w8 = 0; w8 < 8; ++w8) s += P[w8 * 1024 + t];
    const int n = t >> 5, ch = t & 31;  // n = 0..15
    out_sf[((size_t)b * KCL + n) * CCH + chs * 32 + ch] = s * inv;
    if (t < 32) {  // n = 16
      float s2 = 0.f;
      #pragma unroll
      for (int w8 = 0; w8 < 8; ++w8) s2 += P[w8 * 1024 + 512 + t];
      out_sf[((size_t)b * KCL + 16) * CCH + chs * 32 + t] = s2 * inv;
    }
  }
}

extern "C" void kernel_launch(void* const* d_in, const int* in_sizes, int n_in,
                              void* d_out, int out_size, void* d_ws, size_t ws_size,
                              hipStream_t stream) {
  const float* x = (const float*)d_in[0];
  const float* w = (const float*)d_in[1];
  const float* bias = (const float*)d_in[2];
  float* out = (float*)d_out;
  float* outg = out;                 // (32,17)
  float* outsf = out + BATCH * KCL;  // (32,17,512)

  char* ws = (char*)d_ws;
  float* wT = (float*)(ws + WT_OFF);
  unsigned short* sig = (unsigned short*)(ws + SIG_OFF);
  unsigned short* xbf = (unsigned short*)(ws + XBF_OFF);

  k0_setup<<<1, 512, 0, stream>>>(w, wT, outg);

  hipFuncSetAttribute((const void*)k12_cam_sig,
                      hipFuncAttributeMaxDynamicSharedMemorySize, K12_LDS);
  k12_cam_sig<<<BATCH * 8, 512, K12_LDS, stream>>>(x, wT, bias, outg, xbf, sig);

  k3_sf<<<BATCH * 16, 512, 0, stream>>>(xbf, sig, outsf);
}